// Round 10
// baseline (39.188 us; speedup 1.0000x reference)
//
#include <hip/hip_runtime.h>
#include <math.h>

#define EPS_T 1e-4f
#define BIG 1e10f
#define NRM_EPS 1e-12f

// Prep: tb[s] = (cx, cy, cz, -w), w = |c|^2 - r^2.  Staging math verbatim
// from the R9-passed kernel's LDS staging (same expression -> same rounding).
__global__ __launch_bounds__(128) void prep_kernel(
    const float* __restrict__ centers, const float* __restrict__ radii,
    float4* __restrict__ tb)
{
    int s = threadIdx.x;   // 128 threads, 1 block
    float cx = centers[3 * s + 0];
    float cy = centers[3 * s + 1];
    float cz = centers[3 * s + 2];
    float r  = radii[s];
    float w  = cx * cx + cy * cy + cz * cz - r * r;
    tb[s] = make_float4(cx, cy, cz, -w);
}

// ---- inline-asm: 1 sphere per body, constants in SGPRs (scalar pipe) ------
// Work regs v32..v36.  Table groups of 4 spheres double-buffered in
// s[36:51] / s[52:67]; s_load_dwordx16 issued one group ahead; single
// outstanding SMEM -> lgkmcnt(0) drain after current group's compute.
// Rounding forms bit-exact to R6/R9-passed kernels:
//   doc = fma(dx,cx, fma(dy,cy, dz*cz));  ooc likewise
//   bm  = doc + (-od);  ncv = fma(ooc,2,-oo) + (-w);  dsc = fma(bm,bm,ncv)
//   t   = bm - v_sqrt(dsc); dsc<0 -> NaN -> ordered cmps false -> rejected
// Trans hazard: s_nop 1 between v_sqrt and its consumer (proven in R9).
// Single sequential select chain, strict < : exact jnp.argmin semantics.
#define CS(CX, CY, CZ, NW) \
  "v_mul_f32 v32, " CZ ", %[dz]\n\t" \
  "v_mul_f32 v33, " CZ ", %[oz]\n\t" \
  "v_fma_f32 v32, " CY ", %[dy], v32\n\t" \
  "v_fma_f32 v33, " CY ", %[oy], v33\n\t" \
  "v_fma_f32 v32, " CX ", %[dx], v32\n\t" \
  "v_fma_f32 v33, " CX ", %[ox], v33\n\t" \
  "v_add_f32 v34, v32, %[nod]\n\t" \
  "v_fma_f32 v35, v33, 2.0, %[noo]\n\t" \
  "v_add_f32 v35, " NW ", v35\n\t" \
  "v_fma_f32 v35, v34, v34, v35\n\t" \
  "v_sqrt_f32 v36, v35\n\t" \
  "s_nop 1\n\t" \
  "v_sub_f32 v36, v34, v36\n\t" \
  "v_cmp_lt_f32 vcc, %[eps], v36\n\t" \
  "v_cmp_gt_f32 s[20:21], %[tmin], v36\n\t" \
  "s_and_b64 vcc, vcc, s[20:21]\n\t" \
  "v_cndmask_b32 %[tmin], %[tmin], v36, vcc\n\t" \
  "v_cndmask_b32 %[sidx], %[sidx], %[vj], vcc\n\t" \
  "v_add_u32 %[vj], 1, %[vj]\n\t"

#define CGA CS("s36","s37","s38","s39") CS("s40","s41","s42","s43") \
            CS("s44","s45","s46","s47") CS("s48","s49","s50","s51")
#define CGB CS("s52","s53","s54","s55") CS("s56","s57","s58","s59") \
            CS("s60","s61","s62","s63") CS("s64","s65","s66","s67")

#define LDA "s_load_dwordx16 s[36:51], s[30:31], 0x0\n\t" \
            "s_add_u32 s30, s30, 64\n\t" \
            "s_addc_u32 s31, s31, 0\n\t"
#define LDB "s_load_dwordx16 s[52:67], s[30:31], 0x0\n\t" \
            "s_add_u32 s30, s30, 64\n\t" \
            "s_addc_u32 s31, s31, 0\n\t"
#define WL  "s_waitcnt lgkmcnt(0)\n\t"

__global__ __launch_bounds__(256) void illum_kernel(
    const float* __restrict__ ray_o,
    const float* __restrict__ ray_d,
    const float* __restrict__ centers,
    const float* __restrict__ light_pos,
    const int*   __restrict__ light_idx,
    const float* __restrict__ tb,
    float* __restrict__ out,   // [N*3] results, then [N] active(0/1)
    int N)
{
    const int i = blockIdx.x * blockDim.x + threadIdx.x;
    if (i >= N) return;

    float ox = ray_o[3 * i + 0], oy = ray_o[3 * i + 1], oz = ray_o[3 * i + 2];
    float dx = ray_d[3 * i + 0], dy = ray_d[3 * i + 1], dz = ray_d[3 * i + 2];

    // d = normalize(ray_d), precise (once per ray)
    float dn  = sqrtf(dx * dx + dy * dy + dz * dz);
    float din = 1.0f / fmaxf(dn, NRM_EPS);
    dx *= din; dy *= din; dz *= din;

    const float od = ox * dx + oy * dy + oz * dz;
    const float oo = ox * ox + oy * oy + oz * oz;
    const float nod = -od;
    const float noo = -oo;

    float tmin = BIG;
    int sidx = 0, vj = 0;

    asm volatile(
        "s_mov_b64 s[30:31], %[tb]\n\t"
        WL
        LDA                       // group 0 -> A
        WL
        ".rept 15\n\t"            // groups 0..29 (2 per rep)
        LDB CGA WL
        LDA CGB WL
        ".endr\n\t"
        LDB CGA WL                // compute g30, g31 loaded
        CGB                       // compute g31
        : [tmin]"+v"(tmin), [sidx]"+v"(sidx), [vj]"+v"(vj)
        : [dx]"v"(dx), [dy]"v"(dy), [dz]"v"(dz),
          [ox]"v"(ox), [oy]"v"(oy), [oz]"v"(oz),
          [nod]"v"(nod), [noo]"v"(noo),
          [eps]"s"(1e-4f),
          [tb]"s"((unsigned long long)(size_t)tb)
        : "v32","v33","v34","v35","v36",
          "s20","s21","s30","s31",
          "s36","s37","s38","s39","s40","s41","s42","s43",
          "s44","s45","s46","s47","s48","s49","s50","s51",
          "s52","s53","s54","s55","s56","s57","s58","s59",
          "s60","s61","s62","s63","s64","s65","s66","s67",
          "vcc","scc","memory");

    const bool active = (tmin < BIG);

    // hit point
    float px = fmaf(tmin, dx, ox);
    float py = fmaf(tmin, dy, oy);
    float pz = fmaf(tmin, dz, oz);

    // surface normal (center gather from global, L1/L2-resident 1.5 KB)
    float cbx = centers[3 * sidx + 0];
    float cby = centers[3 * sidx + 1];
    float cbz = centers[3 * sidx + 2];
    float nx = px - cbx, ny = py - cby, nz = pz - cbz;
    float nn  = sqrtf(nx * nx + ny * ny + nz * nz);
    float nin = 1.0f / fmaxf(nn, NRM_EPS);
    nx *= nin; ny *= nin; nz *= nin;

    // direction to sampled light
    int li = light_idx[i];
    float dsx = light_pos[3 * li + 0] - px;
    float dsy = light_pos[3 * li + 1] - py;
    float dsz = light_pos[3 * li + 2] - pz;

    // Duff et al. branchless orthonormal frame; local = (d.s, d.t, d.n)
    float sgn = (nz >= 0.0f) ? 1.0f : -1.0f;
    float a   = -1.0f / (sgn + nz);
    float bb  = nx * ny * a;
    float sx = 1.0f + sgn * nx * nx * a, sy = sgn * bb,          sz = -sgn * nx;
    float tx = bb,                       ty = sgn + ny * ny * a, tz = -ny;

    float l0 = dsx * sx + dsy * sy + dsz * sz;
    float l1 = dsx * tx + dsy * ty + dsz * tz;
    float l2 = dsx * nx + dsy * ny + dsz * nz;
    float ln  = sqrtf(l0 * l0 + l1 * l1 + l2 * l2);
    float lin = 1.0f / fmaxf(ln, NRM_EPS);

    float r0 = active ? (l0 * lin + 1.0f) * 0.5f : 0.0f;
    float r1 = active ? (l1 * lin + 1.0f) * 0.5f : 0.0f;
    float r2 = active ? (l2 * lin + 1.0f) * 0.5f : 0.0f;

    out[3 * i + 0] = (1.0f + r0) * 0.5f;
    out[3 * i + 1] = (1.0f + r1) * 0.5f;
    out[3 * i + 2] = (1.0f + r2) * 0.5f;
    out[(size_t)3 * N + i] = active ? 1.0f : 0.0f;
}

extern "C" void kernel_launch(void* const* d_in, const int* in_sizes, int n_in,
                              void* d_out, int out_size, void* d_ws, size_t ws_size,
                              hipStream_t stream) {
    const float* ray_o     = (const float*)d_in[0];
    const float* ray_d     = (const float*)d_in[1];
    const float* centers   = (const float*)d_in[2];
    const float* radii     = (const float*)d_in[3];
    const float* light_pos = (const float*)d_in[4];
    const int*   light_idx = (const int*)d_in[5];
    float* out = (float*)d_out;
    float4* tb = (float4*)d_ws;    // 2 KB table in workspace

    const int N = in_sizes[0] / 3;   // S fixed at 128

    prep_kernel<<<1, 128, 0, stream>>>(centers, radii, tb);

    const int block = 256;
    const int grid  = (N + block - 1) / block;
    illum_kernel<<<grid, block, 0, stream>>>(ray_o, ray_d, centers,
                                             light_pos, light_idx,
                                             (const float*)tb, out, N);
}

// Round 11
// 32.062 us; speedup vs baseline: 1.2223x; 1.2223x over previous
//
#include <hip/hip_runtime.h>
#include <math.h>

#define EPS_T 1e-4f
#define BIG 1e10f
#define NRM_EPS 1e-12f

typedef float v2f __attribute__((ext_vector_type(2)));

// ---- inline-asm pair body (R6-exact math) + 4-deep LDS prefetch ring -----
// Registers (physical, clobbered):
//   v[32:33] U = d.c (packed over 2 spheres)   v[34:35] V = o.c
//   v[36:37] BM = U - od (= -b)                v[38:39] NCV, then DSC
//   BUF0 v[40:47]  BUF1 v[48:55]  BUF2 v[56:63]  BUF3 v[64:71]  (cx2,cy2,cz2,-w2)
//   v72,v73 sqrt / t scratch
// Table per pair j: float4 (x0,x1,y0,y1), float4 (z0,z1,-w0,-w1), w=|c|^2-r^2.
// Rounding forms bit-exact to the R6-passed kernel:
//   doc = fma(dx,cx, fma(dy,cy, dz*cz));  ooc likewise
//   bm  = doc + (-od); ncv = fma(ooc,2,-oo) + (-w); dsc = fma(bm,bm,ncv)
//   t   = bm - v_sqrt(dsc); dsc<0 -> NaN -> ordered cmps false -> rejected
// Ring: steady-state 8 ds_reads outstanding (4 pairs x 2); lgkmcnt(6) pops
// the oldest pair (DS returns in-order; counted-lgkm proven in R9). Prefetch
// distance 3 bodies (~170cyc) > LDS latency (~120cyc) -> no stall.
// Trans hazard: >=1 instr between v_sqrt and consumer (R6-proven; R8 failed
// at 0); drain bodies use s_nop 1 in the PF slot.
#define PF0 \
  "ds_read_b128 v[40:43], %[lda] offset:0\n\t" \
  "ds_read_b128 v[44:47], %[lda] offset:16\n\t" \
  "v_add_u32 %[lda], 32, %[lda]\n\t"
#define PF1 \
  "ds_read_b128 v[48:51], %[lda] offset:0\n\t" \
  "ds_read_b128 v[52:55], %[lda] offset:16\n\t" \
  "v_add_u32 %[lda], 32, %[lda]\n\t"
#define PF2 \
  "ds_read_b128 v[56:59], %[lda] offset:0\n\t" \
  "ds_read_b128 v[60:63], %[lda] offset:16\n\t" \
  "v_add_u32 %[lda], 32, %[lda]\n\t"
#define PF3 \
  "ds_read_b128 v[64:67], %[lda] offset:0\n\t" \
  "ds_read_b128 v[68:71], %[lda] offset:16\n\t" \
  "v_add_u32 %[lda], 32, %[lda]\n\t"

#define PBODY(W, CX, CY, CZ, CWN, PF) \
  W \
  "v_pk_mul_f32 v[32:33], %[dz2], " CZ "\n\t" \
  "v_pk_mul_f32 v[34:35], %[oz2], " CZ "\n\t" \
  "v_pk_fma_f32 v[32:33], %[dy2], " CY ", v[32:33]\n\t" \
  "v_pk_fma_f32 v[34:35], %[oy2], " CY ", v[34:35]\n\t" \
  "v_pk_fma_f32 v[32:33], %[dx2], " CX ", v[32:33]\n\t" \
  "v_pk_fma_f32 v[34:35], %[ox2], " CX ", v[34:35]\n\t" \
  "v_pk_add_f32 v[36:37], v[32:33], %[nod2]\n\t" \
  "v_pk_fma_f32 v[38:39], v[34:35], %[two2], %[noo2]\n\t" \
  "v_pk_add_f32 v[38:39], v[38:39], " CWN "\n\t" \
  PF \
  "v_pk_fma_f32 v[38:39], v[36:37], v[36:37], v[38:39]\n\t" \
  "v_sqrt_f32 v72, v38\n\t" \
  "v_sqrt_f32 v73, v39\n\t" \
  "v_sub_f32 v72, v36, v72\n\t" \
  "v_sub_f32 v73, v37, v73\n\t" \
  "v_cmp_lt_f32 vcc, %[eps], v72\n\t" \
  "v_cmp_gt_f32 s[20:21], %[tme], v72\n\t" \
  "s_and_b64 vcc, vcc, s[20:21]\n\t" \
  "v_cndmask_b32 %[tme], %[tme], v72, vcc\n\t" \
  "v_cndmask_b32 %[ide], %[ide], %[vj], vcc\n\t" \
  "v_cmp_lt_f32 vcc, %[eps], v73\n\t" \
  "v_cmp_gt_f32 s[20:21], %[tmo], v73\n\t" \
  "s_and_b64 vcc, vcc, s[20:21]\n\t" \
  "v_cndmask_b32 %[tmo], %[tmo], v73, vcc\n\t" \
  "v_cndmask_b32 %[ido], %[ido], %[vj], vcc\n\t" \
  "v_add_u32 %[vj], 1, %[vj]\n\t"

#define W6 "s_waitcnt lgkmcnt(6)\n\t"
#define NOP "s_nop 1\n\t"

__global__ __launch_bounds__(256) void illum_kernel(
    const float* __restrict__ ray_o,
    const float* __restrict__ ray_d,
    const float* __restrict__ centers,
    const float* __restrict__ radii,
    const float* __restrict__ light_pos,
    const int*   __restrict__ light_idx,
    float* __restrict__ out,   // [N*3] results, then [N] active(0/1)
    int N)
{
    __shared__ float4 tab[128];   // pair j: tab[2j]=(x0,x1,y0,y1), tab[2j+1]=(z0,z1,-w0,-w1)

    const int tid = threadIdx.x;
    if (tid < 64) {
        float x0 = centers[6 * tid + 0], y0 = centers[6 * tid + 1], z0 = centers[6 * tid + 2];
        float x1 = centers[6 * tid + 3], y1 = centers[6 * tid + 4], z1 = centers[6 * tid + 5];
        float r0 = radii[2 * tid + 0],   r1 = radii[2 * tid + 1];
        float w0 = x0 * x0 + y0 * y0 + z0 * z0 - r0 * r0;
        float w1 = x1 * x1 + y1 * y1 + z1 * z1 - r1 * r1;
        tab[2 * tid + 0] = make_float4(x0, x1, y0, y1);
        tab[2 * tid + 1] = make_float4(z0, z1, -w0, -w1);
    }
    __syncthreads();

    const int i = blockIdx.x * blockDim.x + tid;
    if (i >= N) return;

    float ox = ray_o[3 * i + 0], oy = ray_o[3 * i + 1], oz = ray_o[3 * i + 2];
    float dx = ray_d[3 * i + 0], dy = ray_d[3 * i + 1], dz = ray_d[3 * i + 2];

    // d = normalize(ray_d), precise (once per ray)
    float dn  = sqrtf(dx * dx + dy * dy + dz * dz);
    float din = 1.0f / fmaxf(dn, NRM_EPS);
    dx *= din; dy *= din; dz *= din;

    const float od = ox * dx + oy * dy + oz * dz;
    const float oo = ox * ox + oy * oy + oz * oz;

    v2f dx2 = {dx, dx}, dy2 = {dy, dy}, dz2 = {dz, dz};
    v2f ox2 = {ox, ox}, oy2 = {oy, oy}, oz2 = {oz, oz};
    v2f nod2 = {-od, -od};
    v2f noo2 = {-oo, -oo};
    v2f two2 = {2.0f, 2.0f};

    float tme = BIG, tmo = BIG;
    int ide = 0, ido = 0, vj = 0;
    // generic shared-pointer low 32 bits == LDS byte offset
    unsigned lda = (unsigned)(size_t)&tab[0];

    asm volatile(
        "s_waitcnt lgkmcnt(0)\n\t"
        PF0 PF1 PF2 PF3
        ".rept 15\n\t"                 // pairs 0..59, prefetching 4..63
        PBODY(W6, "v[40:41]", "v[42:43]", "v[44:45]", "v[46:47]", PF0)
        PBODY(W6, "v[48:49]", "v[50:51]", "v[52:53]", "v[54:55]", PF1)
        PBODY(W6, "v[56:57]", "v[58:59]", "v[60:61]", "v[62:63]", PF2)
        PBODY(W6, "v[64:65]", "v[66:67]", "v[68:69]", "v[70:71]", PF3)
        ".endr\n\t"
        // drain: pairs 60..63 (8,6,4,2 reads outstanding before each wait)
        PBODY("s_waitcnt lgkmcnt(6)\n\t", "v[40:41]", "v[42:43]", "v[44:45]", "v[46:47]", NOP)
        PBODY("s_waitcnt lgkmcnt(4)\n\t", "v[48:49]", "v[50:51]", "v[52:53]", "v[54:55]", NOP)
        PBODY("s_waitcnt lgkmcnt(2)\n\t", "v[56:57]", "v[58:59]", "v[60:61]", "v[62:63]", NOP)
        PBODY("s_waitcnt lgkmcnt(0)\n\t", "v[64:65]", "v[66:67]", "v[68:69]", "v[70:71]", NOP)
        : [tme]"+v"(tme), [tmo]"+v"(tmo), [ide]"+v"(ide), [ido]"+v"(ido),
          [vj]"+v"(vj), [lda]"+v"(lda)
        : [dx2]"v"(dx2), [dy2]"v"(dy2), [dz2]"v"(dz2),
          [ox2]"v"(ox2), [oy2]"v"(oy2), [oz2]"v"(oz2),
          [nod2]"v"(nod2), [noo2]"v"(noo2), [two2]"v"(two2),
          [eps]"s"(1e-4f)
        : "v32","v33","v34","v35","v36","v37","v38","v39",
          "v40","v41","v42","v43","v44","v45","v46","v47",
          "v48","v49","v50","v51","v52","v53","v54","v55",
          "v56","v57","v58","v59","v60","v61","v62","v63",
          "v64","v65","v66","v67","v68","v69","v70","v71",
          "v72","v73",
          "s20","s21","vcc","scc","memory");

    // merge chains: even-sphere winner (idx 2*ide) vs odd (2*ido+1),
    // index-aware tie-break preserves jnp.argmin first-occurrence exactly.
    int iE = 2 * ide, iO = 2 * ido + 1;
    bool ow = (tmo < tme) | ((tmo == tme) & (iO < iE));
    float tmin = ow ? tmo : tme;
    int   sidx = ow ? iO  : iE;

    const bool active = (tmin < BIG);

    // hit point
    float px = fmaf(tmin, dx, ox);
    float py = fmaf(tmin, dy, oy);
    float pz = fmaf(tmin, dz, oz);

    // surface normal (center from LDS table)
    float4 ab = tab[2 * (sidx >> 1) + 0];
    float4 zw = tab[2 * (sidx >> 1) + 1];
    float cbx = (sidx & 1) ? ab.y : ab.x;
    float cby = (sidx & 1) ? ab.w : ab.z;
    float cbz = (sidx & 1) ? zw.y : zw.x;
    float nx = px - cbx, ny = py - cby, nz = pz - cbz;
    float nn  = sqrtf(nx * nx + ny * ny + nz * nz);
    float nin = 1.0f / fmaxf(nn, NRM_EPS);
    nx *= nin; ny *= nin; nz *= nin;

    // direction to sampled light
    int li = light_idx[i];
    float dsx = light_pos[3 * li + 0] - px;
    float dsy = light_pos[3 * li + 1] - py;
    float dsz = light_pos[3 * li + 2] - pz;

    // Duff et al. branchless orthonormal frame; local = (d.s, d.t, d.n)
    float sgn = (nz >= 0.0f) ? 1.0f : -1.0f;
    float a   = -1.0f / (sgn + nz);
    float bb  = nx * ny * a;
    float sx = 1.0f + sgn * nx * nx * a, sy = sgn * bb,          sz = -sgn * nx;
    float tx = bb,                       ty = sgn + ny * ny * a, tz = -ny;

    float l0 = dsx * sx + dsy * sy + dsz * sz;
    float l1 = dsx * tx + dsy * ty + dsz * tz;
    float l2 = dsx * nx + dsy * ny + dsz * nz;
    float ln  = sqrtf(l0 * l0 + l1 * l1 + l2 * l2);
    float lin = 1.0f / fmaxf(ln, NRM_EPS);

    float r0 = active ? (l0 * lin + 1.0f) * 0.5f : 0.0f;
    float r1 = active ? (l1 * lin + 1.0f) * 0.5f : 0.0f;
    float r2 = active ? (l2 * lin + 1.0f) * 0.5f : 0.0f;

    out[3 * i + 0] = (1.0f + r0) * 0.5f;
    out[3 * i + 1] = (1.0f + r1) * 0.5f;
    out[3 * i + 2] = (1.0f + r2) * 0.5f;
    out[(size_t)3 * N + i] = active ? 1.0f : 0.0f;
}

extern "C" void kernel_launch(void* const* d_in, const int* in_sizes, int n_in,
                              void* d_out, int out_size, void* d_ws, size_t ws_size,
                              hipStream_t stream) {
    const float* ray_o     = (const float*)d_in[0];
    const float* ray_d     = (const float*)d_in[1];
    const float* centers   = (const float*)d_in[2];
    const float* radii     = (const float*)d_in[3];
    const float* light_pos = (const float*)d_in[4];
    const int*   light_idx = (const int*)d_in[5];
    float* out = (float*)d_out;

    const int N = in_sizes[0] / 3;   // S fixed at 128

    const int block = 256;
    const int grid  = (N + block - 1) / block;
    illum_kernel<<<grid, block, 0, stream>>>(ray_o, ray_d, centers, radii,
                                             light_pos, light_idx, out, N);
}